// Round 15
// baseline (3713.491 us; speedup 1.0000x reference)
//
#include <hip/hip_runtime.h>
#include <hip/hip_bf16.h>
#include <hip/hip_fp16.h>
#include <cstdint>
#include <cstddef>

#define B_  16
#define S_  1024
#define DIN 128
#define H_  256
#define G4  1024
#define GD  256
#define CD  17
#define E_  524288
#define N_  16384

typedef _Float16 f16;
typedef _Float16 f16x2 __attribute__((ext_vector_type(2)));
typedef _Float16 f16x8 __attribute__((ext_vector_type(8)));
typedef float    f32x4 __attribute__((ext_vector_type(4)));

#define DOT2(a, b, c) __builtin_amdgcn_fdot2((a), (b), (c), false)

__device__ __forceinline__ float sigf(float x) { return 1.0f / (1.0f + __expf(-x)); }
__device__ __forceinline__ float tanhfast(float x) { return 1.0f - 2.0f / (__expf(2.0f * x) + 1.0f); }

// ---------------------------------------------------------------------------
__global__ void sentinel_kernel(float* out, float v) {
    out[blockIdx.x * 256 + threadIdx.x] = v;
}

// ---------------------------------------------------------------------------
// CSR build (edge_index: planar int32)
// ---------------------------------------------------------------------------
__global__ void count_kernel(const int* __restrict__ ei, int* __restrict__ cnt) {
    int i = blockIdx.x * 256 + threadIdx.x;
    atomicAdd(&cnt[ei[E_ + i]], 1);
}

__global__ void scan_kernel(const int* __restrict__ cnt, int* __restrict__ offs) {
    __shared__ int sums[1024];
    const int t = threadIdx.x;
    int loc[16];
    int s = 0;
    const int base = t * 16;
#pragma unroll
    for (int i = 0; i < 16; i++) { loc[i] = cnt[base + i]; s += loc[i]; }
    sums[t] = s;
    __syncthreads();
    for (int d = 1; d < 1024; d <<= 1) {
        int v = 0;
        if (t >= d) v = sums[t - d];
        __syncthreads();
        if (t >= d) sums[t] += v;
        __syncthreads();
    }
    int ex = (t == 0) ? 0 : sums[t - 1];
#pragma unroll
    for (int i = 0; i < 16; i++) { offs[base + i] = ex; ex += loc[i]; }
    if (t == 1023) offs[N_] = ex;
}

__global__ void fill_kernel(const int* __restrict__ ei, const int* __restrict__ offs,
                            int* __restrict__ cursor, int* __restrict__ csr) {
    int i = blockIdx.x * 256 + threadIdx.x;
    int dv = ei[E_ + i];
    int p = atomicAdd(&cursor[dv], 1);
    csr[offs[dv] + p] = ei[i];
}

__global__ void inv_kernel(const int* __restrict__ cnt, float* __restrict__ invd) {
    int n = blockIdx.x * 256 + threadIdx.x;
    invd[n] = rsqrtf((float)(cnt[n] + 1));
}

// ---------------------------------------------------------------------------
// conversions / weight prep
// ---------------------------------------------------------------------------
__global__ void cvt16_kernel(const float* __restrict__ src, f16* __restrict__ dst, int n) {
    int i = blockIdx.x * 256 + threadIdx.x;
    if (i < n) dst[i] = (f16)src[i];
}

__global__ void bias_comb_kernel(const float* __restrict__ a, const float* __restrict__ b,
                                 float* __restrict__ o) {
    int i = blockIdx.x * 256 + threadIdx.x;
    o[i] = a[i] + b[i];
}

// W [K][256] f32 -> hi/lo [256][K] f16 (transposed, residual-split)
template <int K>
__global__ void wsplit_kernel(const float* __restrict__ W, f16* __restrict__ hi,
                              f16* __restrict__ lo) {
    int idx = blockIdx.x * 256 + threadIdx.x;  // over K*256
    int k = idx >> 8, n = idx & 255;
    float v = W[idx];
    f16 h = (f16)v;
    hi[(size_t)n * K + k] = h;
    lo[(size_t)n * K + k] = (f16)(v - (float)h);
}

// ---------------------------------------------------------------------------
// MFMA GEMM (unchanged from r12)
// ---------------------------------------------------------------------------
template <int K, bool BIAS, bool RESID, typename OutT>
__global__ __launch_bounds__(256)
void mgemm_kernel(const f16* __restrict__ A, const f16* __restrict__ BT,
                  const f16* __restrict__ BTlo, const float* __restrict__ bias,
                  OutT* __restrict__ C, int ldc)
{
    const int wv = threadIdx.x >> 6, lane = threadIdx.x & 63;
    const int m0 = blockIdx.x * 64 + wv * 16;
    const int n0 = blockIdx.y * 256;
    const int rw = lane & 15, kq = lane >> 4;
    f32x4 acc[16];
#pragma unroll
    for (int t = 0; t < 16; ++t) acc[t] = (f32x4){0.f, 0.f, 0.f, 0.f};

    const f16* __restrict__ Ap = A + (size_t)(m0 + rw) * K + kq * 8;
    for (int k0 = 0; k0 < K; k0 += 32) {
        const f16x8 a = *(const f16x8*)(Ap + k0);
#pragma unroll
        for (int t = 0; t < 16; ++t) {
            const size_t boff = (size_t)(n0 + t * 16 + rw) * K + k0 + kq * 8;
            acc[t] = __builtin_amdgcn_mfma_f32_16x16x32_f16(a, *(const f16x8*)(BT + boff), acc[t], 0, 0, 0);
            if constexpr (RESID) {
                acc[t] = __builtin_amdgcn_mfma_f32_16x16x32_f16(a, *(const f16x8*)(BTlo + boff), acc[t], 0, 0, 0);
            }
        }
    }
    const int orow = m0 + kq * 4;
#pragma unroll
    for (int t = 0; t < 16; ++t) {
        const int col = n0 + t * 16 + rw;
        float bv = 0.f;
        if constexpr (BIAS) bv = bias[col];
#pragma unroll
        for (int r = 0; r < 4; ++r) {
            C[(size_t)(orow + r) * ldc + col] = (OutT)(acc[t][r] + bv);
        }
    }
}

// ---------------------------------------------------------------------------
// LSTM v3 (FIXED): 32 blocks = (dir,batch), 1024 threads = (unit u, gate gq).
// Each thread owns ONE gate row with FULL K=256 (128 f16x2 regs, compiler may
// overflow into AGPRs on gfx950's unified file) -> 128 dot2/thread/step.
// h double-buffer (1 KB LDS) read as pure broadcast (same addr all lanes).
// Gate exchange via 3-shfl butterfly within each lane quad; all 4 lanes
// redundantly compute the bitwise-identical cell update; lane gq==0 writes h.
// r14 BUG WAS HERE: c-loop ran 16 iters (half-K) instead of 32.
// ---------------------------------------------------------------------------
__global__ __launch_bounds__(1024, 1)
void lstm_kernel(const f16* __restrict__ xg,
                 const float* __restrict__ whh_f, const float* __restrict__ whh_r,
                 f16* __restrict__ nodes)
{
    __shared__ __align__(16) f16 hb[2][256];

    const int t = threadIdx.x;
    const int u = t >> 2, gq = t & 3;          // lane&3 == gq (quads lane-aligned)
    const int d = blockIdx.x >> 4, b = blockIdx.x & 15;
    const float* __restrict__ whh = d ? whh_r : whh_f;

    // full K=256 weight row for gate gq (torch order i,f,g,o), unit u
    f16x2 wv[128];
    {
        const float* src = whh + (size_t)(gq * 256 + u) * H_;
#pragma unroll
        for (int c = 0; c < 128; c++) {
            f16x2 w; w[0] = (f16)src[2 * c]; w[1] = (f16)src[2 * c + 1];
            wv[c] = w;
        }
    }
    if (t < 256) { hb[0][t] = (f16)0.f; hb[1][t] = (f16)0.f; }
    __syncthreads();

    float c_st = 0.f;
    const f16* __restrict__ xgb = xg + ((size_t)(d * B_ + b)) * S_ * G4 + gq * 256 + u;
    f16* __restrict__ nb = nodes + (size_t)b * S_ * 512 + d * H_ + u;

    for (int si = 0; si < S_; ++si) {
        const int s = d ? (S_ - 1 - si) : si;
        const int cur = si & 1;

        const float xv = (float)xgb[(size_t)s * G4];

        float a0 = 0.f, a1 = 0.f, a2 = 0.f, a3 = 0.f;
        const f16x8* __restrict__ hp = (const f16x8*)&hb[cur][0];
#pragma unroll
        for (int c = 0; c < 32; c++) {      // FIXED: full K=256 (was 16 -> half-K)
            f16x8 hv = hp[c];
            f16x2 h2;
            h2[0] = hv[0]; h2[1] = hv[1];
            a0 = DOT2(h2, wv[c * 4 + 0], a0);
            h2[0] = hv[2]; h2[1] = hv[3];
            a1 = DOT2(h2, wv[c * 4 + 1], a1);
            h2[0] = hv[4]; h2[1] = hv[5];
            a2 = DOT2(h2, wv[c * 4 + 2], a2);
            h2[0] = hv[6]; h2[1] = hv[7];
            a3 = DOT2(h2, wv[c * 4 + 3], a3);
        }
        const float own = ((a0 + a1) + (a2 + a3)) + xv;

        // butterfly: lane gq ends up with s_k = gatesum[gq^k]
        const float s1 = __shfl_xor(own, 1);
        const float s2 = __shfl_xor(own, 2);
        const float s3 = __shfl_xor(s1, 2);
        const bool b0 = (gq & 1) != 0, b1 = (gq & 2) != 0;
        const float gi = b1 ? (b0 ? s3 : s2) : (b0 ? s1 : own);
        const float gf = b1 ? (b0 ? s2 : s3) : (b0 ? own : s1);
        const float gg = b1 ? (b0 ? s1 : own) : (b0 ? s3 : s2);
        const float go = b1 ? (b0 ? own : s1) : (b0 ? s2 : s3);

        const float ig = sigf(gi);
        const float fg = sigf(gf);
        const float gt = tanhfast(gg);
        const float og = sigf(go);
        c_st = fg * c_st + ig * gt;
        const float h = og * tanhfast(c_st);
        const f16 hfv = (f16)h;

        if (gq == 0) {
            hb[cur ^ 1][u] = hfv;
            nb[(size_t)s * 512] = hfv;
        }
        __syncthreads();
    }
}

// ---------------------------------------------------------------------------
// GCN aggregation (output type templated)
// ---------------------------------------------------------------------------
template <typename OutT>
__global__ __launch_bounds__(256)
void gather_kernel(const float* __restrict__ Hm, const int* __restrict__ csr,
                   const int* __restrict__ offs, const float* __restrict__ inv,
                   const float* __restrict__ bias, OutT* __restrict__ Out) {
    const int wid = threadIdx.x >> 6, lane = threadIdx.x & 63;
    const int n = blockIdx.x * 4 + wid;
    const float invn = inv[n];
    const float4* __restrict__ H4 = (const float4*)Hm;

    float4 v = H4[(size_t)n * 64 + lane];
    const float sw = invn * invn;
    float ax = v.x * sw, ay = v.y * sw, az = v.z * sw, aw = v.w * sw;

    const int e0 = offs[n], e1 = offs[n + 1];
    for (int e = e0; e < e1; ++e) {
        const int src = csr[e];
        const float w = inv[src] * invn;
        float4 hv = H4[(size_t)src * 64 + lane];
        ax = fmaf(hv.x, w, ax);
        ay = fmaf(hv.y, w, ay);
        az = fmaf(hv.z, w, az);
        aw = fmaf(hv.w, w, aw);
    }
    const float4 bv = ((const float4*)bias)[lane];
    OutT* o = Out + (size_t)n * GD + lane * 4;
    o[0] = (OutT)fmaxf(ax + bv.x, 0.f);
    o[1] = (OutT)fmaxf(ay + bv.y, 0.f);
    o[2] = (OutT)fmaxf(az + bv.z, 0.f);
    o[3] = (OutT)fmaxf(aw + bv.w, 0.f);
}

// ---------------------------------------------------------------------------
// classifier: float32 output
// ---------------------------------------------------------------------------
__global__ __launch_bounds__(256)
void cls_kernel(const float* __restrict__ g2, const float* __restrict__ Wc,
                const float* __restrict__ bc, float* __restrict__ out) {
    const int idx = blockIdx.x * 256 + threadIdx.x;
    if (idx >= N_ * CD) return;
    const int n = idx / CD, c = idx % CD;
    const float* __restrict__ row = g2 + (size_t)n * GD;
    float a0 = bc[c], a1 = 0.f, a2 = 0.f, a3 = 0.f;
    for (int k = 0; k < GD; k += 4) {
        a0 = fmaf(row[k + 0], Wc[(size_t)(k + 0) * CD + c], a0);
        a1 = fmaf(row[k + 1], Wc[(size_t)(k + 1) * CD + c], a1);
        a2 = fmaf(row[k + 2], Wc[(size_t)(k + 2) * CD + c], a2);
        a3 = fmaf(row[k + 3], Wc[(size_t)(k + 3) * CD + c], a3);
    }
    out[idx] = (a0 + a1) + (a2 + a3);
}

// ---------------------------------------------------------------------------
extern "C" void kernel_launch(void* const* d_in, const int* in_sizes, int n_in,
                              void* d_out, int out_size, void* d_ws, size_t ws_size,
                              hipStream_t stream) {
    const float* x     = (const float*)d_in[0];
    const int*   ei    = (const int*)d_in[1];
    const float* wih_f = (const float*)d_in[2];
    const float* whh_f = (const float*)d_in[3];
    const float* bih_f = (const float*)d_in[4];
    const float* bhh_f = (const float*)d_in[5];
    const float* wih_r = (const float*)d_in[6];
    const float* whh_r = (const float*)d_in[7];
    const float* bih_r = (const float*)d_in[8];
    const float* bhh_r = (const float*)d_in[9];
    const float* W1    = (const float*)d_in[10];
    const float* b1    = (const float*)d_in[11];
    const float* W2    = (const float*)d_in[12];
    const float* b2    = (const float*)d_in[13];
    const float* Wc    = (const float*)d_in[14];
    const float* bc    = (const float*)d_in[15];
    float* out = (float*)d_out;
    (void)out_size;

    static const int EXP_SIZES[16] = {
        2097152, 1048576, 131072, 262144, 1024, 1024,
        131072, 262144, 1024, 1024, 131072, 256, 65536, 256, 4352, 17
    };
    if (n_in != 16) { sentinel_kernel<<<4, 256, 0, stream>>>(out, 3.5e6f); return; }
    for (int i = 0; i < 16; ++i) {
        if (in_sizes[i] != EXP_SIZES[i]) {
            sentinel_kernel<<<4, 256, 0, stream>>>(out, 1.0e6f + (float)(i + 1) * 1.0e5f);
            return;
        }
    }

    // ---- workspace (86.25 MB footprint proven since r3) ----
    char* ws = (char*)d_ws;
    size_t off = 0;
    auto alloc = [&](size_t bytes) -> char* {
        char* p = ws + off;
        off = (off + bytes + 255) & ~(size_t)255;
        return p;
    };
    f16*   xg     = (f16*)  alloc((size_t)2 * B_ * S_ * G4 * sizeof(f16));  // 67.1 MB
    f16*   nodes  = (f16*)  alloc((size_t)N_ * 512 * sizeof(f16));          // 16.8 MB
    int*   cnt    = (int*)  alloc((size_t)N_ * 4);
    float* invd   = (float*)alloc((size_t)N_ * 4);
    int*   offs   = (int*)  alloc((size_t)(N_ + 1) * 4);
    int*   cursor = (int*)  alloc((size_t)N_ * 4);
    int*   csr    = (int*)  alloc((size_t)E_ * 4);
    const size_t NEED = off;

    // pre-LSTM tenants of the nodes region
    char* nreg = (char*)nodes;
    f16*   xf16   = (f16*)  (nreg);
    f16*   wih16f = (f16*)  (nreg + 4300800);
    f16*   wih16r = (f16*)  (nreg + 4300800 + 270336);
    float* biasf  = (float*)(nreg + 4300800 + 2 * 270336);
    float* biasr  = (float*)(nreg + 4300800 + 2 * 270336 + 8192);

    // post-LSTM tenants of the xg region
    char* xreg = (char*)xg;
    float* h1 = (float*)(xreg);
    f16*   g1 = (f16*)  (xreg + 16777216);
    float* g2 = (float*)(xreg + 16777216 + 8388608);
    f16*   W1Thi = (f16*)(xreg + 50331648);
    f16*   W1Tlo = (f16*)(xreg + 50331648 + 262144);
    f16*   W2Thi = (f16*)(xreg + 50331648 + 2 * 262144);
    f16*   W2Tlo = (f16*)(xreg + 50331648 + 2 * 262144 + 131072);

    if (ws_size < NEED) {
        sentinel_kernel<<<4, 256, 0, stream>>>(out, 1.0e6f + 1000.0f * (float)(ws_size >> 20));
        return;
    }

    hipMemsetAsync(cnt, 0, (size_t)N_ * 4, stream);
    hipMemsetAsync(cursor, 0, (size_t)N_ * 4, stream);

    // graph
    count_kernel<<<E_ / 256, 256, 0, stream>>>(ei, cnt);
    scan_kernel<<<1, 1024, 0, stream>>>(cnt, offs);
    fill_kernel<<<E_ / 256, 256, 0, stream>>>(ei, offs, cursor, csr);
    inv_kernel<<<N_ / 256, 256, 0, stream>>>(cnt, invd);

    // input conversions
    cvt16_kernel<<<(2097152 + 255) / 256, 256, 0, stream>>>(x, xf16, 2097152);
    cvt16_kernel<<<(131072 + 255) / 256, 256, 0, stream>>>(wih_f, wih16f, 131072);
    cvt16_kernel<<<(131072 + 255) / 256, 256, 0, stream>>>(wih_r, wih16r, 131072);
    bias_comb_kernel<<<4, 256, 0, stream>>>(bih_f, bhh_f, biasf);
    bias_comb_kernel<<<4, 256, 0, stream>>>(bih_r, bhh_r, biasr);

    // xg = x @ wih^T + bias
    mgemm_kernel<128, true, false, f16><<<dim3(256, 4), 256, 0, stream>>>(
        xf16, wih16f, nullptr, biasf, xg, G4);
    mgemm_kernel<128, true, false, f16><<<dim3(256, 4), 256, 0, stream>>>(
        xf16, wih16r, nullptr, biasr, xg + (size_t)B_ * S_ * G4, G4);

    lstm_kernel<<<32, 1024, 0, stream>>>(xg, whh_f, whh_r, nodes);

    // weight prep for GCN gemms (into now-dead xg region)
    wsplit_kernel<512><<<512 * 256 / 256, 256, 0, stream>>>(W1, W1Thi, W1Tlo);
    wsplit_kernel<256><<<256 * 256 / 256, 256, 0, stream>>>(W2, W2Thi, W2Tlo);

    mgemm_kernel<512, false, true, float><<<dim3(256, 1), 256, 0, stream>>>(
        nodes, W1Thi, W1Tlo, nullptr, h1, GD);
    gather_kernel<f16><<<N_ / 4, 256, 0, stream>>>(h1, csr, offs, invd, b1, g1);
    mgemm_kernel<256, false, true, float><<<dim3(256, 1), 256, 0, stream>>>(
        g1, W2Thi, W2Tlo, nullptr, h1, GD);
    gather_kernel<float><<<N_ / 4, 256, 0, stream>>>(h1, csr, offs, invd, b2, g2);
    cls_kernel<<<(N_ * CD + 255) / 256, 256, 0, stream>>>(g2, Wc, bc, out);
}

// Round 16
// 2199.527 us; speedup vs baseline: 1.6883x; 1.6883x over previous
//
#include <hip/hip_runtime.h>
#include <hip/hip_bf16.h>
#include <hip/hip_fp16.h>
#include <cstdint>
#include <cstddef>

#define B_  16
#define S_  1024
#define DIN 128
#define H_  256
#define G4  1024
#define GD  256
#define CD  17
#define E_  524288
#define N_  16384

typedef _Float16 f16;
typedef _Float16 f16x2 __attribute__((ext_vector_type(2)));
typedef _Float16 f16x8 __attribute__((ext_vector_type(8)));
typedef float    f32x4 __attribute__((ext_vector_type(4)));

#define DOT2(a, b, c) __builtin_amdgcn_fdot2((a), (b), (c), false)

__device__ __forceinline__ float sigf(float x) { return 1.0f / (1.0f + __expf(-x)); }
__device__ __forceinline__ float tanhfast(float x) { return 1.0f - 2.0f / (__expf(2.0f * x) + 1.0f); }

// ---------------------------------------------------------------------------
__global__ void sentinel_kernel(float* out, float v) {
    out[blockIdx.x * 256 + threadIdx.x] = v;
}

// ---------------------------------------------------------------------------
// CSR build (edge_index: planar int32)
// ---------------------------------------------------------------------------
__global__ void count_kernel(const int* __restrict__ ei, int* __restrict__ cnt) {
    int i = blockIdx.x * 256 + threadIdx.x;
    atomicAdd(&cnt[ei[E_ + i]], 1);
}

__global__ void scan_kernel(const int* __restrict__ cnt, int* __restrict__ offs) {
    __shared__ int sums[1024];
    const int t = threadIdx.x;
    int loc[16];
    int s = 0;
    const int base = t * 16;
#pragma unroll
    for (int i = 0; i < 16; i++) { loc[i] = cnt[base + i]; s += loc[i]; }
    sums[t] = s;
    __syncthreads();
    for (int d = 1; d < 1024; d <<= 1) {
        int v = 0;
        if (t >= d) v = sums[t - d];
        __syncthreads();
        if (t >= d) sums[t] += v;
        __syncthreads();
    }
    int ex = (t == 0) ? 0 : sums[t - 1];
#pragma unroll
    for (int i = 0; i < 16; i++) { offs[base + i] = ex; ex += loc[i]; }
    if (t == 1023) offs[N_] = ex;
}

__global__ void fill_kernel(const int* __restrict__ ei, const int* __restrict__ offs,
                            int* __restrict__ cursor, int* __restrict__ csr) {
    int i = blockIdx.x * 256 + threadIdx.x;
    int dv = ei[E_ + i];
    int p = atomicAdd(&cursor[dv], 1);
    csr[offs[dv] + p] = ei[i];
}

__global__ void inv_kernel(const int* __restrict__ cnt, float* __restrict__ invd) {
    int n = blockIdx.x * 256 + threadIdx.x;
    invd[n] = rsqrtf((float)(cnt[n] + 1));
}

// ---------------------------------------------------------------------------
// conversions / weight prep
// ---------------------------------------------------------------------------
__global__ void cvt16_kernel(const float* __restrict__ src, f16* __restrict__ dst, int n) {
    int i = blockIdx.x * 256 + threadIdx.x;
    if (i < n) dst[i] = (f16)src[i];
}

__global__ void bias_comb_kernel(const float* __restrict__ a, const float* __restrict__ b,
                                 float* __restrict__ o) {
    int i = blockIdx.x * 256 + threadIdx.x;
    o[i] = a[i] + b[i];
}

// W [K][256] f32 -> hi/lo [256][K] f16 (transposed, residual-split)
template <int K>
__global__ void wsplit_kernel(const float* __restrict__ W, f16* __restrict__ hi,
                              f16* __restrict__ lo) {
    int idx = blockIdx.x * 256 + threadIdx.x;  // over K*256
    int k = idx >> 8, n = idx & 255;
    float v = W[idx];
    f16 h = (f16)v;
    hi[(size_t)n * K + k] = h;
    lo[(size_t)n * K + k] = (f16)(v - (float)h);
}

// ---------------------------------------------------------------------------
// MFMA GEMM (unchanged from r12)
// ---------------------------------------------------------------------------
template <int K, bool BIAS, bool RESID, typename OutT>
__global__ __launch_bounds__(256)
void mgemm_kernel(const f16* __restrict__ A, const f16* __restrict__ BT,
                  const f16* __restrict__ BTlo, const float* __restrict__ bias,
                  OutT* __restrict__ C, int ldc)
{
    const int wv = threadIdx.x >> 6, lane = threadIdx.x & 63;
    const int m0 = blockIdx.x * 64 + wv * 16;
    const int n0 = blockIdx.y * 256;
    const int rw = lane & 15, kq = lane >> 4;
    f32x4 acc[16];
#pragma unroll
    for (int t = 0; t < 16; ++t) acc[t] = (f32x4){0.f, 0.f, 0.f, 0.f};

    const f16* __restrict__ Ap = A + (size_t)(m0 + rw) * K + kq * 8;
    for (int k0 = 0; k0 < K; k0 += 32) {
        const f16x8 a = *(const f16x8*)(Ap + k0);
#pragma unroll
        for (int t = 0; t < 16; ++t) {
            const size_t boff = (size_t)(n0 + t * 16 + rw) * K + k0 + kq * 8;
            acc[t] = __builtin_amdgcn_mfma_f32_16x16x32_f16(a, *(const f16x8*)(BT + boff), acc[t], 0, 0, 0);
            if constexpr (RESID) {
                acc[t] = __builtin_amdgcn_mfma_f32_16x16x32_f16(a, *(const f16x8*)(BTlo + boff), acc[t], 0, 0, 0);
            }
        }
    }
    const int orow = m0 + kq * 4;
#pragma unroll
    for (int t = 0; t < 16; ++t) {
        const int col = n0 + t * 16 + rw;
        float bv = 0.f;
        if constexpr (BIAS) bv = bias[col];
#pragma unroll
        for (int r = 0; r < 4; ++r) {
            C[(size_t)(orow + r) * ldc + col] = (OutT)(acc[t][r] + bv);
        }
    }
}

// ---------------------------------------------------------------------------
// LSTM (r13 structure + light barrier + xg prefetch):
// 32 blocks = (dir,batch), 512 threads = (unit u, K-half kh).
// i/f/o half-rows in 192 VGPRs; g half-rows in rotation-swizzled LDS;
// h f16 double-buffer (per-kh halves, skewed).
// NEW vs r13: (1) barrier = s_waitcnt lgkmcnt(0) + s_barrier (no vmcnt drain
// -> nb stores / xg loads pipeline across steps); (2) next-step xg values
// prefetched as raw f16 before the dot loop (HBM latency hidden under
// ~2500 cyc of compute).
// ---------------------------------------------------------------------------
__global__ __launch_bounds__(512, 2)
void lstm_kernel(const f16* __restrict__ xg,
                 const float* __restrict__ whh_f, const float* __restrict__ whh_r,
                 f16* __restrict__ nodes)
{
    __shared__ __align__(16) f16x2 gw[256 * 2 * 64];  // 128 KB g-rows, rotated
    __shared__ __align__(16) f16 hb[2][2][136];       // [buf][half][128+pad]

    const int t = threadIdx.x;
    const int u = t >> 1, kh = t & 1;
    const int row = u * 2 + kh;
    const int rot = row & 15;
    const int d = blockIdx.x >> 4, b = blockIdx.x & 15;
    const float* __restrict__ whh = d ? whh_r : whh_f;

    // i,f,o half-rows -> registers as packed f16 pairs
    f16x2 wr[3][64];
    {
        const int rws[3] = {u, 256 + u, 768 + u};
#pragma unroll
        for (int r = 0; r < 3; r++) {
            const float* src = whh + (size_t)rws[r] * H_ + kh * 128;
#pragma unroll
            for (int c = 0; c < 64; c++) {
                f16x2 w; w[0] = (f16)src[2 * c]; w[1] = (f16)src[2 * c + 1];
                wr[r][c] = w;
            }
        }
    }
    // g half-row -> LDS with granule rotation (bank-uniform)
    {
        const float* src = whh + (size_t)(512 + u) * H_ + kh * 128;
        f16x2* dst = gw + (size_t)row * 64;
#pragma unroll
        for (int lw = 0; lw < 64; ++lw) {
            int phys = ((((lw >> 2) + rot) & 15) << 2) | (lw & 3);
            f16x2 w; w[0] = (f16)src[2 * lw]; w[1] = (f16)src[2 * lw + 1];
            dst[phys] = w;
        }
    }
    if (t < 136) {
        hb[0][0][t] = (f16)0.f; hb[0][1][t] = (f16)0.f;
        hb[1][0][t] = (f16)0.f; hb[1][1][t] = (f16)0.f;
    }
    __syncthreads();

    float c_st = 0.f;
    const f16* __restrict__ xgb = xg + ((size_t)(d * B_ + b)) * S_ * G4;
    f16* __restrict__ nb = nodes + (size_t)b * S_ * 512 + d * H_;

    // prefetch step 0
    f16 pxi, pxf, pxg, pxo;
    {
        const f16* xr = xgb + (size_t)(d ? (S_ - 1) : 0) * G4 + u;
        pxi = xr[0]; pxf = xr[256]; pxg = xr[512]; pxo = xr[768];
    }

    for (int si = 0; si < S_; ++si) {
        const int s = d ? (S_ - 1 - si) : si;
        const int cur = si & 1;

        const float xi = (float)pxi;
        const float xf = (float)pxf;
        const float xg_ = (float)pxg;
        const float xo = (float)pxo;

        // issue next step's xg loads (in flight during the dot loop)
        if (si + 1 < S_) {
            const int s2 = d ? (S_ - 2 - si) : (si + 1);
            const f16* xr2 = xgb + (size_t)s2 * G4 + u;
            pxi = xr2[0]; pxf = xr2[256]; pxg = xr2[512]; pxo = xr2[768];
        }

        float a0 = 0.f, a1 = 0.f, a2 = 0.f, a3 = 0.f;
        float a4 = 0.f, a5 = 0.f, a6 = 0.f, a7 = 0.f;
        const f16x8* hp = (const f16x8*)&hb[cur][kh][0];
        const f16x8* gp = (const f16x8*)(gw + (size_t)row * 64);

#pragma unroll
        for (int c = 0; c < 4; c++) {
#pragma unroll
            for (int j = 0; j < 4; j++) {
                f16x8 hv = hp[c * 4 + j];
                f16x8 gv = gp[((c * 4 + j) + rot) & 15];
#pragma unroll
                for (int p = 0; p < 4; p++) {
                    f16x2 h2; h2[0] = hv[2 * p]; h2[1] = hv[2 * p + 1];
                    f16x2 g2; g2[0] = gv[2 * p]; g2[1] = gv[2 * p + 1];
                    const int w = c * 16 + j * 4 + p;
                    if (p & 1) {
                        a1 = DOT2(h2, wr[0][w], a1);
                        a3 = DOT2(h2, wr[1][w], a3);
                        a5 = DOT2(h2, wr[2][w], a5);
                        a7 = DOT2(h2, g2, a7);
                    } else {
                        a0 = DOT2(h2, wr[0][w], a0);
                        a2 = DOT2(h2, wr[1][w], a2);
                        a4 = DOT2(h2, wr[2][w], a4);
                        a6 = DOT2(h2, g2, a6);
                    }
                }
            }
        }
        float ti = a0 + a1, tf = a2 + a3, to = a4 + a5, tg = a6 + a7;
        ti += __shfl_xor(ti, 1);
        tf += __shfl_xor(tf, 1);
        to += __shfl_xor(to, 1);
        tg += __shfl_xor(tg, 1);

        const float ig = sigf(xi + ti);
        const float fg = sigf(xf + tf);
        const float gt = tanhfast(xg_ + tg);
        const float og = sigf(xo + to);
        c_st = fg * c_st + ig * gt;
        const float h = og * tanhfast(c_st);
        const f16 hfv = (f16)h;

        if (kh == 0) {
            hb[cur ^ 1][u >> 7][u & 127] = hfv;
            nb[(size_t)s * 512 + u] = hfv;
        }
        // light barrier: LDS visibility only (no vmcnt drain — stores and
        // prefetch loads stay in flight across steps)
        asm volatile("s_waitcnt lgkmcnt(0)" ::: "memory");
        __builtin_amdgcn_s_barrier();
    }
}

// ---------------------------------------------------------------------------
// GCN aggregation (output type templated)
// ---------------------------------------------------------------------------
template <typename OutT>
__global__ __launch_bounds__(256)
void gather_kernel(const float* __restrict__ Hm, const int* __restrict__ csr,
                   const int* __restrict__ offs, const float* __restrict__ inv,
                   const float* __restrict__ bias, OutT* __restrict__ Out) {
    const int wid = threadIdx.x >> 6, lane = threadIdx.x & 63;
    const int n = blockIdx.x * 4 + wid;
    const float invn = inv[n];
    const float4* __restrict__ H4 = (const float4*)Hm;

    float4 v = H4[(size_t)n * 64 + lane];
    const float sw = invn * invn;
    float ax = v.x * sw, ay = v.y * sw, az = v.z * sw, aw = v.w * sw;

    const int e0 = offs[n], e1 = offs[n + 1];
    for (int e = e0; e < e1; ++e) {
        const int src = csr[e];
        const float w = inv[src] * invn;
        float4 hv = H4[(size_t)src * 64 + lane];
        ax = fmaf(hv.x, w, ax);
        ay = fmaf(hv.y, w, ay);
        az = fmaf(hv.z, w, az);
        aw = fmaf(hv.w, w, aw);
    }
    const float4 bv = ((const float4*)bias)[lane];
    OutT* o = Out + (size_t)n * GD + lane * 4;
    o[0] = (OutT)fmaxf(ax + bv.x, 0.f);
    o[1] = (OutT)fmaxf(ay + bv.y, 0.f);
    o[2] = (OutT)fmaxf(az + bv.z, 0.f);
    o[3] = (OutT)fmaxf(aw + bv.w, 0.f);
}

// ---------------------------------------------------------------------------
// classifier: float32 output
// ---------------------------------------------------------------------------
__global__ __launch_bounds__(256)
void cls_kernel(const float* __restrict__ g2, const float* __restrict__ Wc,
                const float* __restrict__ bc, float* __restrict__ out) {
    const int idx = blockIdx.x * 256 + threadIdx.x;
    if (idx >= N_ * CD) return;
    const int n = idx / CD, c = idx % CD;
    const float* __restrict__ row = g2 + (size_t)n * GD;
    float a0 = bc[c], a1 = 0.f, a2 = 0.f, a3 = 0.f;
    for (int k = 0; k < GD; k += 4) {
        a0 = fmaf(row[k + 0], Wc[(size_t)(k + 0) * CD + c], a0);
        a1 = fmaf(row[k + 1], Wc[(size_t)(k + 1) * CD + c], a1);
        a2 = fmaf(row[k + 2], Wc[(size_t)(k + 2) * CD + c], a2);
        a3 = fmaf(row[k + 3], Wc[(size_t)(k + 3) * CD + c], a3);
    }
    out[idx] = (a0 + a1) + (a2 + a3);
}

// ---------------------------------------------------------------------------
extern "C" void kernel_launch(void* const* d_in, const int* in_sizes, int n_in,
                              void* d_out, int out_size, void* d_ws, size_t ws_size,
                              hipStream_t stream) {
    const float* x     = (const float*)d_in[0];
    const int*   ei    = (const int*)d_in[1];
    const float* wih_f = (const float*)d_in[2];
    const float* whh_f = (const float*)d_in[3];
    const float* bih_f = (const float*)d_in[4];
    const float* bhh_f = (const float*)d_in[5];
    const float* wih_r = (const float*)d_in[6];
    const float* whh_r = (const float*)d_in[7];
    const float* bih_r = (const float*)d_in[8];
    const float* bhh_r = (const float*)d_in[9];
    const float* W1    = (const float*)d_in[10];
    const float* b1    = (const float*)d_in[11];
    const float* W2    = (const float*)d_in[12];
    const float* b2    = (const float*)d_in[13];
    const float* Wc    = (const float*)d_in[14];
    const float* bc    = (const float*)d_in[15];
    float* out = (float*)d_out;
    (void)out_size;

    static const int EXP_SIZES[16] = {
        2097152, 1048576, 131072, 262144, 1024, 1024,
        131072, 262144, 1024, 1024, 131072, 256, 65536, 256, 4352, 17
    };
    if (n_in != 16) { sentinel_kernel<<<4, 256, 0, stream>>>(out, 3.5e6f); return; }
    for (int i = 0; i < 16; ++i) {
        if (in_sizes[i] != EXP_SIZES[i]) {
            sentinel_kernel<<<4, 256, 0, stream>>>(out, 1.0e6f + (float)(i + 1) * 1.0e5f);
            return;
        }
    }

    // ---- workspace (86.25 MB footprint proven since r3) ----
    char* ws = (char*)d_ws;
    size_t off = 0;
    auto alloc = [&](size_t bytes) -> char* {
        char* p = ws + off;
        off = (off + bytes + 255) & ~(size_t)255;
        return p;
    };
    f16*   xg     = (f16*)  alloc((size_t)2 * B_ * S_ * G4 * sizeof(f16));  // 67.1 MB
    f16*   nodes  = (f16*)  alloc((size_t)N_ * 512 * sizeof(f16));          // 16.8 MB
    int*   cnt    = (int*)  alloc((size_t)N_ * 4);
    float* invd   = (float*)alloc((size_t)N_ * 4);
    int*   offs   = (int*)  alloc((size_t)(N_ + 1) * 4);
    int*   cursor = (int*)  alloc((size_t)N_ * 4);
    int*   csr    = (int*)  alloc((size_t)E_ * 4);
    const size_t NEED = off;

    // pre-LSTM tenants of the nodes region
    char* nreg = (char*)nodes;
    f16*   xf16   = (f16*)  (nreg);
    f16*   wih16f = (f16*)  (nreg + 4300800);
    f16*   wih16r = (f16*)  (nreg + 4300800 + 270336);
    float* biasf  = (float*)(nreg + 4300800 + 2 * 270336);
    float* biasr  = (float*)(nreg + 4300800 + 2 * 270336 + 8192);

    // post-LSTM tenants of the xg region
    char* xreg = (char*)xg;
    float* h1 = (float*)(xreg);
    f16*   g1 = (f16*)  (xreg + 16777216);
    float* g2 = (float*)(xreg + 16777216 + 8388608);
    f16*   W1Thi = (f16*)(xreg + 50331648);
    f16*   W1Tlo = (f16*)(xreg + 50331648 + 262144);
    f16*   W2Thi = (f16*)(xreg + 50331648 + 2 * 262144);
    f16*   W2Tlo = (f16*)(xreg + 50331648 + 2 * 262144 + 131072);

    if (ws_size < NEED) {
        sentinel_kernel<<<4, 256, 0, stream>>>(out, 1.0e6f + 1000.0f * (float)(ws_size >> 20));
        return;
    }

    hipMemsetAsync(cnt, 0, (size_t)N_ * 4, stream);
    hipMemsetAsync(cursor, 0, (size_t)N_ * 4, stream);

    // graph
    count_kernel<<<E_ / 256, 256, 0, stream>>>(ei, cnt);
    scan_kernel<<<1, 1024, 0, stream>>>(cnt, offs);
    fill_kernel<<<E_ / 256, 256, 0, stream>>>(ei, offs, cursor, csr);
    inv_kernel<<<N_ / 256, 256, 0, stream>>>(cnt, invd);

    // input conversions
    cvt16_kernel<<<(2097152 + 255) / 256, 256, 0, stream>>>(x, xf16, 2097152);
    cvt16_kernel<<<(131072 + 255) / 256, 256, 0, stream>>>(wih_f, wih16f, 131072);
    cvt16_kernel<<<(131072 + 255) / 256, 256, 0, stream>>>(wih_r, wih16r, 131072);
    bias_comb_kernel<<<4, 256, 0, stream>>>(bih_f, bhh_f, biasf);
    bias_comb_kernel<<<4, 256, 0, stream>>>(bih_r, bhh_r, biasr);

    // xg = x @ wih^T + bias
    mgemm_kernel<128, true, false, f16><<<dim3(256, 4), 256, 0, stream>>>(
        xf16, wih16f, nullptr, biasf, xg, G4);
    mgemm_kernel<128, true, false, f16><<<dim3(256, 4), 256, 0, stream>>>(
        xf16, wih16r, nullptr, biasr, xg + (size_t)B_ * S_ * G4, G4);

    lstm_kernel<<<32, 512, 0, stream>>>(xg, whh_f, whh_r, nodes);

    // weight prep for GCN gemms (into now-dead xg region)
    wsplit_kernel<512><<<512 * 256 / 256, 256, 0, stream>>>(W1, W1Thi, W1Tlo);
    wsplit_kernel<256><<<256 * 256 / 256, 256, 0, stream>>>(W2, W2Thi, W2Tlo);

    mgemm_kernel<512, false, true, float><<<dim3(256, 1), 256, 0, stream>>>(
        nodes, W1Thi, W1Tlo, nullptr, h1, GD);
    gather_kernel<f16><<<N_ / 4, 256, 0, stream>>>(h1, csr, offs, invd, b1, g1);
    mgemm_kernel<256, false, true, float><<<dim3(256, 1), 256, 0, stream>>>(
        g1, W2Thi, W2Tlo, nullptr, h1, GD);
    gather_kernel<float><<<N_ / 4, 256, 0, stream>>>(h1, csr, offs, invd, b2, g2);
    cls_kernel<<<(N_ * CD + 255) / 256, 256, 0, stream>>>(g2, Wc, bc, out);
}